// Round 10
// baseline (445.950 us; speedup 1.0000x reference)
//
#include <hip/hip_runtime.h>
#include <hip/hip_bf16.h>

#define NB 4
#define LSEQ 2048
#define NROWS (NB * LSEQ)        // 8192
#define DMODEL 512
#define DINNER 1024
#define NSTATE 16
#define DTRANK 32
#define LN_EPS 1e-5f

#define NCHUNK 64
#define TCHUNK 32               // NCHUNK * TCHUNK == LSEQ

typedef _Float16 f16;
typedef _Float16 f16x2 __attribute__((ext_vector_type(2)));
typedef _Float16 f16x4 __attribute__((ext_vector_type(4)));
typedef _Float16 f16x8 __attribute__((ext_vector_type(8)));
typedef float f32x4 __attribute__((ext_vector_type(4)));

#define AS1 __attribute__((address_space(1)))
#define AS3 __attribute__((address_space(3)))

// ---------------------------------------------------------------- utilities
__device__ inline float wave_sum(float v) {
#pragma unroll
    for (int off = 32; off; off >>= 1) v += __shfl_xor(v, off, 64);
    return v;
}

__device__ inline void load8(float* dst, const float* src) {
    float4* d4 = (float4*)dst; const float4* s4 = (const float4*)src;
    d4[0] = s4[0]; d4[1] = s4[1];
}

// ---------------------------------------------------------------- prep: LN(x)->f16  +  all weight cvt
__global__ __launch_bounds__(256) void prep(const float* __restrict__ x,
                                            const float* __restrict__ w,
                                            const float* __restrict__ b,
                                            f16* __restrict__ out,
                                            const float* __restrict__ ip, const float* __restrict__ xp,
                                            const float* __restrict__ dt, const float* __restrict__ mo,
                                            const float* __restrict__ ma, const float* __restrict__ ge,
                                            f16* __restrict__ wout) {
    if (blockIdx.x < NROWS / 4) {
        int row = blockIdx.x * 4 + (threadIdx.x >> 6);
        int lane = threadIdx.x & 63;
        const float* xr = x + (size_t)row * DMODEL + lane * 8;
        float vv[8];
        *(float4*)(vv) = *(const float4*)(xr);
        *(float4*)(vv + 4) = *(const float4*)(xr + 4);
        float s = 0.f, sq = 0.f;
#pragma unroll
        for (int j = 0; j < 8; ++j) { s += vv[j]; sq += vv[j] * vv[j]; }
        s = wave_sum(s); sq = wave_sum(sq);
        float mu = s * (1.f / DMODEL);
        float rstd = rsqrtf(sq * (1.f / DMODEL) - mu * mu + LN_EPS);
        f16x8 o;
#pragma unroll
        for (int j = 0; j < 8; ++j) {
            int c = lane * 8 + j;
            o[j] = (f16)((vv[j] - mu) * rstd * w[c] + b[c]);
        }
        *(f16x8*)(out + (size_t)row * DMODEL + lane * 8) = o;
    } else {
        int i = (blockIdx.x - NROWS / 4) * 256 + threadIdx.x;
        int stride = (gridDim.x - NROWS / 4) * 256;
        for (; i < 2129920; i += stride) {
            float v;
            if (i < 1048576) v = ip[i];
            else if (i < 1179648) { int j = i - 1048576; v = (j < 65536) ? xp[j] : 0.f; }
            else if (i < 1212416) v = dt[i - 1179648];
            else if (i < 1736704) v = mo[i - 1212416];
            else if (i < 1998848) v = ma[i - 1736704];
            else v = ge[i - 1998848];
            wout[i] = (f16)v;
        }
    }
}

// ---------------------------------------------------------------- GEMM: C[M,N] = X[M,K] @ W[N,K]^T
// 128x128 tile, BK=32, 4 waves; global_load_lds staging; 3-deep counted-vmcnt pipeline.
// MODE 1: f16 out | 2: f16x2 {softplus(v+bias), sigmoid(-(v+bias))} | 3: f32 out(ld128) + f16 aux col<32
template <int MODE>
__global__ __launch_bounds__(256) void gemm_xwt(const f16* __restrict__ X,
                                                const f16* __restrict__ W,
                                                void* __restrict__ Out,
                                                int K, int ldc,
                                                const float* __restrict__ bias,
                                                f16* __restrict__ aux) {
    __shared__ __align__(16) f16 As[2][128 * 32];
    __shared__ __align__(16) f16 Bs[2][128 * 32];
    const int tid = threadIdx.x;
    const int lane = tid & 63;
    const int wv = tid >> 6;
    const int wr = wv >> 1, wc = wv & 1;
    const int rowbase = blockIdx.y * 128;
    const int colbase = blockIdx.x * 128;

    const f32x4 zero = {0.f, 0.f, 0.f, 0.f};
    f32x4 acc[4][4];
#pragma unroll
    for (int m = 0; m < 4; ++m)
#pragma unroll
        for (int n = 0; n < 4; ++n) acc[m][n] = zero;

    const int nk = K >> 5;
    auto stage = [&](int buf, int kt) {
        const int k0 = kt << 5;
#pragma unroll
        for (int it = 0; it < 2; ++it) {
            int id = it * 256 + wv * 64 + lane;
            int row = id >> 2;
            int k8 = (id & 3) << 3;
            const f16* ga = X + (size_t)(rowbase + row) * K + k0 + k8;
            const f16* gb = W + (size_t)(colbase + row) * K + k0 + k8;
            __builtin_amdgcn_global_load_lds(
                (const AS1 void*)ga,
                (AS3 void*)(&As[buf][(it * 256 + wv * 64) * 8]), 16, 0, 0);
            __builtin_amdgcn_global_load_lds(
                (const AS1 void*)gb,
                (AS3 void*)(&Bs[buf][(it * 256 + wv * 64) * 8]), 16, 0, 0);
        }
    };

    stage(0, 0);
    if (nk > 1) stage(1, 1);
    for (int kt = 0; kt < nk; ++kt) {
        const int cur = kt & 1;
        if (kt + 1 < nk) { asm volatile("s_waitcnt vmcnt(4)" ::: "memory"); }
        else             { asm volatile("s_waitcnt vmcnt(0)" ::: "memory"); }
        asm volatile("s_barrier" ::: "memory");

        f16x8 af[4], bf[4];
#pragma unroll
        for (int m = 0; m < 4; ++m)
            af[m] = *(const f16x8*)(&As[cur][(wr * 64 + m * 16 + (lane & 15)) * 32 + ((lane >> 4) << 3)]);
#pragma unroll
        for (int n = 0; n < 4; ++n)
            bf[n] = *(const f16x8*)(&Bs[cur][(wc * 64 + n * 16 + (lane & 15)) * 32 + ((lane >> 4) << 3)]);
#pragma unroll
        for (int m = 0; m < 4; ++m)
#pragma unroll
            for (int n = 0; n < 4; ++n)
                acc[m][n] = __builtin_amdgcn_mfma_f32_16x16x32_f16(af[m], bf[n], acc[m][n], 0, 0, 0);

        asm volatile("s_waitcnt lgkmcnt(0)" ::: "memory");
        asm volatile("s_barrier" ::: "memory");
        if (kt + 2 < nk) stage(cur, kt + 2);
    }
#pragma unroll
    for (int m = 0; m < 4; ++m) {
        int r0 = rowbase + wr * 64 + m * 16 + ((lane >> 4) << 2);
#pragma unroll
        for (int n = 0; n < 4; ++n) {
            int c = colbase + wc * 64 + n * 16 + (lane & 15);
#pragma unroll
            for (int r = 0; r < 4; ++r) {
                float v = acc[m][n][r];
                size_t o = (size_t)(r0 + r) * ldc + c;
                if (MODE == 1) {
                    ((f16*)Out)[o] = (f16)v;
                } else if (MODE == 2) {
                    float t = v + bias[c];
                    float dl = fmaxf(t, 0.f) + log1pf(__expf(-fabsf(t)));
                    float e1 = 1.f / (1.f + __expf(t));      // exp(-softplus(t))
                    f16x2 pk; pk[0] = (f16)dl; pk[1] = (f16)e1;
                    ((f16x2*)Out)[o] = pk;
                } else if (MODE == 3) {
                    ((float*)Out)[o] = v;
                    if (c < DTRANK) aux[(size_t)(r0 + r) * DTRANK + c] = (f16)v;
                }
            }
        }
    }
}

// ---------------------------------------------------------------- causal depthwise conv + silu
// 4 consecutive rows x 8 channels per thread: 7-row sliding window, reads 28B/output vs 64B.
__global__ __launch_bounds__(256) void conv_silu(const f16* __restrict__ xz,
                                                 const float* __restrict__ cw,
                                                 const float* __restrict__ cb,
                                                 f16* __restrict__ out16) {
    int i = blockIdx.x * 256 + threadIdx.x;          // 0 .. 262143
    int dg = i & 127;                                // channel group (8 ch)
    int rg = i >> 7;                                 // row group (4 rows)
    int row0 = rg * 4;
    int t0 = row0 & (LSEQ - 1);
    int d0 = dg * 8;

    f16x8 wnd[7];
#pragma unroll
    for (int j = 0; j < 7; ++j) {
        if (j < 3 && t0 == 0) {
#pragma unroll
            for (int c = 0; c < 8; ++c) wnd[j][c] = (f16)0.f;
        } else {
            wnd[j] = *(const f16x8*)(xz + (size_t)(row0 - 3 + j) * (2 * DINNER) + d0);
        }
    }
    float4 cwv[8]; float cbv[8];
#pragma unroll
    for (int c = 0; c < 8; ++c) {
        cwv[c] = *(const float4*)(cw + (d0 + c) * 4);
        cbv[c] = cb[d0 + c];
    }
#pragma unroll
    for (int k = 0; k < 4; ++k) {
        f16x8 o;
#pragma unroll
        for (int c = 0; c < 8; ++c) {
            float acc = cbv[c];
#pragma unroll
            for (int j = 0; j < 4; ++j) acc += cwv[c][j] * (float)wnd[k + j][c];
            float s = acc / (1.f + __expf(-acc));
            o[c] = (f16)s;
        }
        *(f16x8*)(out16 + (size_t)(row0 + k) * DINNER + d0) = o;
    }
}

// ---------------------------------------------------------------- chunked scan (split-state + FULL register staging)
__device__ inline void pow8(float e1, float* p) {
    p[0] = e1; p[1] = e1 * e1; p[2] = p[0] * p[1]; p[3] = p[1] * p[1];
    p[4] = p[0] * p[3]; p[5] = p[1] * p[3]; p[6] = p[2] * p[3]; p[7] = p[3] * p[3];
}

// pass 1: per (b, chunk, d) local scan from h=0; store end state + sum(delta)
__global__ __launch_bounds__(256) void scan_pass1(const f16x2* __restrict__ de,
                                                  const f16* __restrict__ u,
                                                  const float* __restrict__ xdbl,
                                                  const float* __restrict__ A_log,
                                                  float* __restrict__ hloc,
                                                  float* __restrict__ sumdelta) {
    __shared__ __align__(16) float bc[TCHUNK][32];
    int blk = blockIdx.x;
    int dg = blk & 7;
    int c = (blk >> 3) & (NCHUNK - 1);
    int b = blk >> 9;
    int wv = threadIdx.x >> 6, lane = threadIdx.x & 63;
    int half = lane >> 5;
    int d = dg * 128 + wv * 32 + (lane & 31);
    int n0 = half * 8;
    size_t rbase = (size_t)b * LSEQ + (size_t)c * TCHUNK;

    {   // stage B+C panel
        int trow = threadIdx.x >> 3;
        int q = (threadIdx.x & 7) << 2;
        *(float4*)&bc[trow][q] = *(const float4*)(xdbl + (rbase + trow) * 128 + 32 + q);
    }

    // full register staging of the per-thread streams (all loads in flight at once)
    const f16x2* dp = de + rbase * DINNER + d;
    const f16* up = u + rbase * DINNER + d;
    f16x2 adv[TCHUNK];
    f16 auu[TCHUNK];
#pragma unroll
    for (int t = 0; t < TCHUNK; ++t) adv[t] = dp[(size_t)t * DINNER];
#pragma unroll
    for (int t = 0; t < TCHUNK; ++t) auu[t] = up[(size_t)t * DINNER];

    float A[8];
    bool fast = true;
#pragma unroll
    for (int j = 0; j < 8; ++j) {
        float a = __expf(A_log[d * NSTATE + n0 + j]);
        A[j] = -a;
        float tgt = (float)(n0 + j + 1);
        fast = fast && (fabsf(a - tgt) <= 1e-3f * tgt);
    }
    float h[8];
#pragma unroll
    for (int j = 0; j < 8; ++j) h[j] = 0.f;

    __syncthreads();

    float sd = 0.f;
    if (fast) {
#pragma unroll
        for (int t = 0; t < TCHUNK; ++t) {
            float Bv[8]; load8(Bv, &bc[t][n0]);
            float del = (float)adv[t][0], e1 = (float)adv[t][1];
            float uu = (float)auu[t];
            sd += del;
            float du = del * uu;
            float p[8]; pow8(e1, p);
            float f = half ? p[7] : 1.f;
#pragma unroll
            for (int j = 0; j < 8; ++j)
                h[j] = (p[j] * f) * h[j] + du * Bv[j];
        }
    } else {
#pragma unroll
        for (int t = 0; t < TCHUNK; ++t) {
            float Bv[8]; load8(Bv, &bc[t][n0]);
            float del = (float)adv[t][0];
            float uu = (float)auu[t];
            sd += del;
            float du = del * uu;
#pragma unroll
            for (int j = 0; j < 8; ++j)
                h[j] = __expf(del * A[j]) * h[j] + du * Bv[j];
        }
    }
    size_t idx = ((size_t)(b * NCHUNK + c) * DINNER + d) * NSTATE + n0;
    *(float4*)(hloc + idx) = *(float4*)(h);
    *(float4*)(hloc + idx + 4) = *(float4*)(h + 4);
    if (half == 0) sumdelta[((size_t)(b * NCHUNK + c) * DINNER + d)] = sd;
}

// combine: one thread per (b,d,n); serial over chunks; IN PLACE: hloc[c] := state BEFORE chunk c
__global__ __launch_bounds__(256) void scan_combine(float* __restrict__ hloc,
                                                    const float* __restrict__ sumdelta,
                                                    const float* __restrict__ A_log) {
    int g = blockIdx.x * 256 + threadIdx.x;
    int n = g & 15;
    int d = (g >> 4) & (DINNER - 1);
    int b = g >> 14;
    float A = -__expf(A_log[d * NSTATE + n]);
    float h = 0.f;
    for (int c = 0; c < NCHUNK; ++c) {
        size_t idx = ((size_t)(b * NCHUNK + c) * DINNER + d) * NSTATE + n;
        float loc = hloc[idx];
        hloc[idx] = h;
        h = __expf(A * sumdelta[((size_t)(b * NCHUNK + c) * DINNER + d)]) * h + loc;
    }
}

// pass 2: rerun scan with true h0 (in hloc), compute y, fuse *silu(z); y16 written IN PLACE over u
__global__ __launch_bounds__(256) void scan_pass2(const f16x2* __restrict__ de,
                                                  const f16* __restrict__ u,
                                                  const float* __restrict__ xdbl,
                                                  const float* __restrict__ A_log,
                                                  const float* __restrict__ Dv,
                                                  const float* __restrict__ h0,
                                                  const f16* __restrict__ xz,
                                                  f16* __restrict__ y16) {
    __shared__ __align__(16) float bc[TCHUNK][32];
    int blk = blockIdx.x;
    int dg = blk & 7;
    int c = (blk >> 3) & (NCHUNK - 1);
    int b = blk >> 9;
    int wv = threadIdx.x >> 6, lane = threadIdx.x & 63;
    int half = lane >> 5;
    int d = dg * 128 + wv * 32 + (lane & 31);
    int n0 = half * 8;
    size_t rbase = (size_t)b * LSEQ + (size_t)c * TCHUNK;

    {
        int trow = threadIdx.x >> 3;
        int q = (threadIdx.x & 7) << 2;
        *(float4*)&bc[trow][q] = *(const float4*)(xdbl + (rbase + trow) * 128 + 32 + q);
    }

    const f16x2* dp = de + rbase * DINNER + d;
    const f16* up = u + rbase * DINNER + d;
    const f16* zp = xz + rbase * (2 * DINNER) + DINNER + d;
    f16* yp = y16 + rbase * DINNER + d;

    f16x2 adv[TCHUNK];
    f16 auu[TCHUNK];
    f16 az[TCHUNK];
#pragma unroll
    for (int t = 0; t < TCHUNK; ++t) adv[t] = dp[(size_t)t * DINNER];
#pragma unroll
    for (int t = 0; t < TCHUNK; ++t) auu[t] = up[(size_t)t * DINNER];
#pragma unroll
    for (int t = 0; t < TCHUNK; ++t) az[t] = zp[(size_t)t * (2 * DINNER)];

    float A[8];
    bool fast = true;
#pragma unroll
    for (int j = 0; j < 8; ++j) {
        float a = __expf(A_log[d * NSTATE + n0 + j]);
        A[j] = -a;
        float tgt = (float)(n0 + j + 1);
        fast = fast && (fabsf(a - tgt) <= 1e-3f * tgt);
    }
    float Dval = Dv[d];
    float h[8];
    size_t idx = ((size_t)(b * NCHUNK + c) * DINNER + d) * NSTATE + n0;
    *(float4*)(h) = *(const float4*)(h0 + idx);
    *(float4*)(h + 4) = *(const float4*)(h0 + idx + 4);

    __syncthreads();

    if (fast) {
#pragma unroll
        for (int t = 0; t < TCHUNK; ++t) {
            float Bv[8], Cv[8];
            load8(Bv, &bc[t][n0]);
            load8(Cv, &bc[t][16 + n0]);
            float del = (float)adv[t][0], e1 = (float)adv[t][1];
            float uu = (float)auu[t];
            float du = del * uu;
            float yv = 0.f;
            float p[8]; pow8(e1, p);
            float f = half ? p[7] : 1.f;
#pragma unroll
            for (int j = 0; j < 8; ++j) {
                h[j] = (p[j] * f) * h[j] + du * Bv[j];
                yv += h[j] * Cv[j];
            }
            yv += __shfl_xor(yv, 32, 64);
            yv += uu * Dval;
            float z = (float)az[t];
            float sz = z / (1.f + __expf(-z));
            if (half == 0)
                yp[(size_t)t * DINNER] = (f16)(yv * sz);
        }
    } else {
#pragma unroll
        for (int t = 0; t < TCHUNK; ++t) {
            float Bv[8], Cv[8];
            load8(Bv, &bc[t][n0]);
            load8(Cv, &bc[t][16 + n0]);
            float del = (float)adv[t][0];
            float uu = (float)auu[t];
            float du = del * uu;
            float yv = 0.f;
#pragma unroll
            for (int j = 0; j < 8; ++j) {
                h[j] = __expf(del * A[j]) * h[j] + du * Bv[j];
                yv += h[j] * Cv[j];
            }
            yv += __shfl_xor(yv, 32, 64);
            yv += uu * Dval;
            float z = (float)az[t];
            float sz = z / (1.f + __expf(-z));
            if (half == 0)
                yp[(size_t)t * DINNER] = (f16)(yv * sz);
        }
    }
}

// ---------------------------------------------------------------- fused output LNs (traw in f16, ld 768)
__global__ __launch_bounds__(256) void ln_outputs(const float* __restrict__ x,
                                                  const f16* __restrict__ traw,
                                                  const float* __restrict__ mb,
                                                  const float* __restrict__ gb,
                                                  const float* __restrict__ wm,
                                                  const float* __restrict__ bm,
                                                  const float* __restrict__ wg,
                                                  const float* __restrict__ bg,
                                                  float* __restrict__ out0,
                                                  float* __restrict__ out1) {
    int bid = blockIdx.x;
    int lane = threadIdx.x & 63;
    if (bid < NROWS / 4) {
        int row = bid * 4 + (threadIdx.x >> 6);
        f16x8 t8 = *(const f16x8*)(traw + (size_t)row * 768 + lane * 8);
        float vv[8];
#pragma unroll
        for (int j = 0; j < 8; ++j) {
            int c = lane * 8 + j;
            vv[j] = x[(size_t)row * DMODEL + c] + (float)t8[j] + mb[c];
        }
        float s = 0.f, sq = 0.f;
#pragma unroll
        for (int j = 0; j < 8; ++j) { s += vv[j]; sq += vv[j] * vv[j]; }
        s = wave_sum(s); sq = wave_sum(sq);
        float mu = s * (1.f / DMODEL);
        float rstd = rsqrtf(sq * (1.f / DMODEL) - mu * mu + LN_EPS);
        float ov[8];
#pragma unroll
        for (int j = 0; j < 8; ++j) {
            int c = lane * 8 + j;
            ov[j] = (vv[j] - mu) * rstd * wm[c] + bm[c];
        }
        float* op = out0 + (size_t)row * DMODEL + lane * 8;
        *(float4*)(op) = *(float4*)(ov);
        *(float4*)(op + 4) = *(float4*)(ov + 4);
    } else {
        const int DG = 256;
        int row = (bid - NROWS / 4) * 4 + (threadIdx.x >> 6);
        f16x4 t4 = *(const f16x4*)(traw + (size_t)row * 768 + 512 + lane * 4);
        float vv[4];
#pragma unroll
        for (int j = 0; j < 4; ++j) {
            int c = lane * 4 + j;
            vv[j] = (float)t4[j] + gb[c];
        }
        float s = 0.f, sq = 0.f;
#pragma unroll
        for (int j = 0; j < 4; ++j) { s += vv[j]; sq += vv[j] * vv[j]; }
        s = wave_sum(s); sq = wave_sum(sq);
        float mu = s * (1.f / DG);
        float rstd = rsqrtf(sq * (1.f / DG) - mu * mu + LN_EPS);
        float ov[4];
#pragma unroll
        for (int j = 0; j < 4; ++j) {
            int c = lane * 4 + j;
            ov[j] = (vv[j] - mu) * rstd * wg[c] + bg[c];
        }
        *(float4*)(out1 + (size_t)row * DG + lane * 4) = *(float4*)(ov);
    }
}

// ---------------------------------------------------------------- launcher
extern "C" void kernel_launch(void* const* d_in, const int* in_sizes, int n_in,
                              void* d_out, int out_size, void* d_ws, size_t ws_size,
                              hipStream_t stream) {
    const float* x         = (const float*)d_in[0];
    const float* norm_w    = (const float*)d_in[1];
    const float* norm_b    = (const float*)d_in[2];
    const float* in_proj_w = (const float*)d_in[3];
    const float* conv_w    = (const float*)d_in[4];
    const float* conv_b    = (const float*)d_in[5];
    const float* x_proj_w  = (const float*)d_in[6];
    const float* dt_proj_w = (const float*)d_in[7];
    const float* dt_proj_b = (const float*)d_in[8];
    const float* A_log     = (const float*)d_in[9];
    const float* Dvec      = (const float*)d_in[10];
    const float* mix_out_w = (const float*)d_in[11];
    const float* match_w   = (const float*)d_in[12];
    const float* match_b   = (const float*)d_in[13];
    const float* geom_w    = (const float*)d_in[14];
    const float* geom_b    = (const float*)d_in[15];
    const float* normm_w   = (const float*)d_in[16];
    const float* normm_b   = (const float*)d_in[17];
    const float* normg_w   = (const float*)d_in[18];
    const float* normg_b   = (const float*)d_in[19];

    char* ws = (char*)d_ws;
    f16* h16    = (f16*)(ws + 0);            // 8 MB  (reused: sumdelta during scan, hm16 after)
    f16* wip    = (f16*)(ws + 8388608);      // weights contiguous from here
    f16* wxp    = (f16*)(ws + 10485760);
    f16* wdt    = (f16*)(ws + 10747904);
    f16* wmo    = (f16*)(ws + 10813440);
    f16* wma    = (f16*)(ws + 11862016);     // match+geom contiguous: (768, 512)
    f16* xz16   = (f16*)(ws + 12648448);     // 32 MB
    f16* xmc16  = (f16*)(ws + 46202880);     // 16 MB: u (f16); pass2 writes y16 IN PLACE here
    f16* traw16 = (f16*)(ws + 62980096);     // 12.6 MB: traw (8192x768 f16)
    float* xdbl = (float*)(ws + 96534528);   // 4 MB
    f16* dt16   = (f16*)(ws + 100728832);    // 512 KB
    f16x2* de   = (f16x2*)(ws + 101253120);  // 32 MB: packed {delta, exp(-delta)}

    float* hloc     = (float*)d_out;         // 16.8 MB scratch in d_out (25.2 MB)
    float* sumdelta = (float*)h16;

    f16* hm16 = h16;
    f16* y16 = xmc16;                        // in-place over u
    float* out0 = (float*)d_out;
    float* out1 = out0 + (size_t)NROWS * DMODEL;

    // 1. LN(x) -> h16  +  weight conversions (fused)
    prep<<<NROWS / 4 + 1024, 256, 0, stream>>>(x, norm_w, norm_b, h16,
                                               in_proj_w, x_proj_w, dt_proj_w,
                                               mix_out_w, match_w, geom_w, wip);
    // 2. xz = h @ in_proj^T
    gemm_xwt<1><<<dim3(16, 64), 256, 0, stream>>>(h16, wip, xz16, 512, 2048, nullptr, nullptr);
    // 3. conv + silu -> u (f16)
    conv_silu<<<1024, 256, 0, stream>>>(xz16, conv_w, conv_b, xmc16);
    // 4. x_dbl = xm @ x_proj^T (f32 ld128) + dt16 fused
    gemm_xwt<3><<<dim3(1, 64), 256, 0, stream>>>(xmc16, wxp, xdbl, 1024, 128, nullptr, dt16);
    // 5. de = {softplus(dt @ dt_proj^T + b), exp(-softplus)}  (f16x2 out)
    gemm_xwt<2><<<dim3(8, 64), 256, 0, stream>>>(dt16, wdt, de, 32, 1024, dt_proj_b, nullptr);
    // 6. chunked selective scan (split-state, full register staging)
    scan_pass1<<<NB * NCHUNK * 8, 256, 0, stream>>>(de, xmc16, xdbl, A_log, hloc, sumdelta);
    scan_combine<<<NB * DINNER * NSTATE / 256, 256, 0, stream>>>(hloc, sumdelta, A_log);
    scan_pass2<<<NB * NCHUNK * 8, 256, 0, stream>>>(de, xmc16, xdbl, A_log, Dvec, hloc, xz16, y16);
    // 7. hm = y @ mix_out^T
    gemm_xwt<1><<<dim3(4, 64), 256, 0, stream>>>(y16, wmo, hm16, 1024, 512, nullptr, nullptr);
    // 8. match+geom fused GEMM (N=768, f16 out)
    gemm_xwt<1><<<dim3(6, 64), 256, 0, stream>>>(hm16, wma, traw16, 512, 768, nullptr, nullptr);
    // 9. fused output layernorms (d_out; hloc dead by now)
    ln_outputs<<<NROWS / 2, 256, 0, stream>>>(x, traw16, match_b, geom_b,
                                              normm_w, normm_b, normg_w, normg_b, out0, out1);
}

// Round 11
// 305.978 us; speedup vs baseline: 1.4575x; 1.4575x over previous
//
#include <hip/hip_runtime.h>
#include <hip/hip_bf16.h>

#define NB 4
#define LSEQ 2048
#define NROWS (NB * LSEQ)        // 8192
#define DMODEL 512
#define DINNER 1024
#define NSTATE 16
#define DTRANK 32
#define LN_EPS 1e-5f

#define NCHUNK 64
#define TCHUNK 32               // NCHUNK * TCHUNK == LSEQ

typedef _Float16 f16;
typedef _Float16 f16x2 __attribute__((ext_vector_type(2)));
typedef _Float16 f16x4 __attribute__((ext_vector_type(4)));
typedef _Float16 f16x8 __attribute__((ext_vector_type(8)));
typedef float f32x4 __attribute__((ext_vector_type(4)));

#define AS1 __attribute__((address_space(1)))
#define AS3 __attribute__((address_space(3)))

// ---------------------------------------------------------------- utilities
__device__ inline float wave_sum(float v) {
#pragma unroll
    for (int off = 32; off; off >>= 1) v += __shfl_xor(v, off, 64);
    return v;
}

__device__ inline void load8(float* dst, const float* src) {
    float4* d4 = (float4*)dst; const float4* s4 = (const float4*)src;
    d4[0] = s4[0]; d4[1] = s4[1];
}

// ---------------------------------------------------------------- prep: LN(x)->f16  +  all weight cvt
__global__ __launch_bounds__(256) void prep(const float* __restrict__ x,
                                            const float* __restrict__ w,
                                            const float* __restrict__ b,
                                            f16* __restrict__ out,
                                            const float* __restrict__ ip, const float* __restrict__ xp,
                                            const float* __restrict__ dt, const float* __restrict__ mo,
                                            const float* __restrict__ ma, const float* __restrict__ ge,
                                            f16* __restrict__ wout) {
    if (blockIdx.x < NROWS / 4) {
        int row = blockIdx.x * 4 + (threadIdx.x >> 6);
        int lane = threadIdx.x & 63;
        const float* xr = x + (size_t)row * DMODEL + lane * 8;
        float vv[8];
        *(float4*)(vv) = *(const float4*)(xr);
        *(float4*)(vv + 4) = *(const float4*)(xr + 4);
        float s = 0.f, sq = 0.f;
#pragma unroll
        for (int j = 0; j < 8; ++j) { s += vv[j]; sq += vv[j] * vv[j]; }
        s = wave_sum(s); sq = wave_sum(sq);
        float mu = s * (1.f / DMODEL);
        float rstd = rsqrtf(sq * (1.f / DMODEL) - mu * mu + LN_EPS);
        f16x8 o;
#pragma unroll
        for (int j = 0; j < 8; ++j) {
            int c = lane * 8 + j;
            o[j] = (f16)((vv[j] - mu) * rstd * w[c] + b[c]);
        }
        *(f16x8*)(out + (size_t)row * DMODEL + lane * 8) = o;
    } else {
        int i = (blockIdx.x - NROWS / 4) * 256 + threadIdx.x;
        int stride = (gridDim.x - NROWS / 4) * 256;
        for (; i < 2129920; i += stride) {
            float v;
            if (i < 1048576) v = ip[i];
            else if (i < 1179648) { int j = i - 1048576; v = (j < 65536) ? xp[j] : 0.f; }
            else if (i < 1212416) v = dt[i - 1179648];
            else if (i < 1736704) v = mo[i - 1212416];
            else if (i < 1998848) v = ma[i - 1736704];
            else v = ge[i - 1998848];
            wout[i] = (f16)v;
        }
    }
}

// ---------------------------------------------------------------- GEMM: C[M,N] = X[M,K] @ W[N,K]^T
// 128x128 tile, BK=32, 4 waves; global_load_lds staging; 3-deep counted-vmcnt pipeline.
// MODE 1: f16 out | 3: f32 out(ld128) + f16 aux col<32
template <int MODE>
__global__ __launch_bounds__(256) void gemm_xwt(const f16* __restrict__ X,
                                                const f16* __restrict__ W,
                                                void* __restrict__ Out,
                                                int K, int ldc,
                                                f16* __restrict__ aux) {
    __shared__ __align__(16) f16 As[2][128 * 32];
    __shared__ __align__(16) f16 Bs[2][128 * 32];
    const int tid = threadIdx.x;
    const int lane = tid & 63;
    const int wv = tid >> 6;
    const int wr = wv >> 1, wc = wv & 1;
    const int rowbase = blockIdx.y * 128;
    const int colbase = blockIdx.x * 128;

    const f32x4 zero = {0.f, 0.f, 0.f, 0.f};
    f32x4 acc[4][4];
#pragma unroll
    for (int m = 0; m < 4; ++m)
#pragma unroll
        for (int n = 0; n < 4; ++n) acc[m][n] = zero;

    const int nk = K >> 5;
    auto stage = [&](int buf, int kt) {
        const int k0 = kt << 5;
#pragma unroll
        for (int it = 0; it < 2; ++it) {
            int id = it * 256 + wv * 64 + lane;
            int row = id >> 2;
            int k8 = (id & 3) << 3;
            const f16* ga = X + (size_t)(rowbase + row) * K + k0 + k8;
            const f16* gb = W + (size_t)(colbase + row) * K + k0 + k8;
            __builtin_amdgcn_global_load_lds(
                (const AS1 void*)ga,
                (AS3 void*)(&As[buf][(it * 256 + wv * 64) * 8]), 16, 0, 0);
            __builtin_amdgcn_global_load_lds(
                (const AS1 void*)gb,
                (AS3 void*)(&Bs[buf][(it * 256 + wv * 64) * 8]), 16, 0, 0);
        }
    };

    stage(0, 0);
    if (nk > 1) stage(1, 1);
    for (int kt = 0; kt < nk; ++kt) {
        const int cur = kt & 1;
        if (kt + 1 < nk) { asm volatile("s_waitcnt vmcnt(4)" ::: "memory"); }
        else             { asm volatile("s_waitcnt vmcnt(0)" ::: "memory"); }
        asm volatile("s_barrier" ::: "memory");

        f16x8 af[4], bf[4];
#pragma unroll
        for (int m = 0; m < 4; ++m)
            af[m] = *(const f16x8*)(&As[cur][(wr * 64 + m * 16 + (lane & 15)) * 32 + ((lane >> 4) << 3)]);
#pragma unroll
        for (int n = 0; n < 4; ++n)
            bf[n] = *(const f16x8*)(&Bs[cur][(wc * 64 + n * 16 + (lane & 15)) * 32 + ((lane >> 4) << 3)]);
#pragma unroll
        for (int m = 0; m < 4; ++m)
#pragma unroll
            for (int n = 0; n < 4; ++n)
                acc[m][n] = __builtin_amdgcn_mfma_f32_16x16x32_f16(af[m], bf[n], acc[m][n], 0, 0, 0);

        asm volatile("s_waitcnt lgkmcnt(0)" ::: "memory");
        asm volatile("s_barrier" ::: "memory");
        if (kt + 2 < nk) stage(cur, kt + 2);
    }
#pragma unroll
    for (int m = 0; m < 4; ++m) {
        int r0 = rowbase + wr * 64 + m * 16 + ((lane >> 4) << 2);
#pragma unroll
        for (int n = 0; n < 4; ++n) {
            int c = colbase + wc * 64 + n * 16 + (lane & 15);
#pragma unroll
            for (int r = 0; r < 4; ++r) {
                float v = acc[m][n][r];
                size_t o = (size_t)(r0 + r) * ldc + c;
                if (MODE == 1) {
                    ((f16*)Out)[o] = (f16)v;
                } else if (MODE == 3) {
                    ((float*)Out)[o] = v;
                    if (c < DTRANK) aux[(size_t)(r0 + r) * DTRANK + c] = (f16)v;
                }
            }
        }
    }
}

// ---------------------------------------------------------------- dt_proj + softplus (dedicated small-K kernel)
// de[r][c] = {softplus(t), exp(-softplus(t))},  t = dot(dt16[r], wdt[c]) + bias[c]
// block: 256 cols x 64 rows; dt rows staged to LDS (f32, broadcast reads); w col in regs.
__global__ __launch_bounds__(256) void dt_delta(const f16* __restrict__ dt16,  // (8192, 32)
                                                const f16* __restrict__ wdt,   // (1024, 32)
                                                const float* __restrict__ bias,
                                                f16x2* __restrict__ de) {      // (8192, 1024)
    __shared__ float sdt[64][32];        // 8 KB
    int c = blockIdx.x * 256 + threadIdx.x;
    int r0 = blockIdx.y * 64;
    {
        int row = threadIdx.x >> 2;
        int q = (threadIdx.x & 3) * 8;
        f16x8 v = *(const f16x8*)(dt16 + (size_t)(r0 + row) * DTRANK + q);
#pragma unroll
        for (int j = 0; j < 8; ++j) sdt[row][q + j] = (float)v[j];
    }
    float wv[32];
#pragma unroll
    for (int qq = 0; qq < 4; ++qq) {
        f16x8 v = *(const f16x8*)(wdt + (size_t)c * DTRANK + qq * 8);
#pragma unroll
        for (int j = 0; j < 8; ++j) wv[qq * 8 + j] = (float)v[j];
    }
    float bs = bias[c];
    __syncthreads();

    for (int r = 0; r < 64; ++r) {
        float acc = bs;
#pragma unroll
        for (int k = 0; k < 32; ++k) acc += sdt[r][k] * wv[k];
        float dl, e1;
        if (acc > 20.f) {                      // softplus(t)≈t; avoid exp overflow
            dl = acc; e1 = __expf(-acc);
        } else {
            float et = __expf(acc);
            e1 = 1.f / (1.f + et);             // exp(-softplus(t)) = sigmoid(-t)
            dl = -__logf(e1);                  // softplus(t)
        }
        f16x2 pk; pk[0] = (f16)dl; pk[1] = (f16)e1;
        de[(size_t)(r0 + r) * DINNER + c] = pk;
    }
}

// ---------------------------------------------------------------- causal depthwise conv + silu
// 4 consecutive rows x 8 channels per thread: 7-row sliding window.
__global__ __launch_bounds__(256) void conv_silu(const f16* __restrict__ xz,
                                                 const float* __restrict__ cw,
                                                 const float* __restrict__ cb,
                                                 f16* __restrict__ out16) {
    int i = blockIdx.x * 256 + threadIdx.x;          // 0 .. 262143
    int dg = i & 127;                                // channel group (8 ch)
    int rg = i >> 7;                                 // row group (4 rows)
    int row0 = rg * 4;
    int t0 = row0 & (LSEQ - 1);
    int d0 = dg * 8;

    f16x8 wnd[7];
#pragma unroll
    for (int j = 0; j < 7; ++j) {
        if (j < 3 && t0 == 0) {
#pragma unroll
            for (int c = 0; c < 8; ++c) wnd[j][c] = (f16)0.f;
        } else {
            wnd[j] = *(const f16x8*)(xz + (size_t)(row0 - 3 + j) * (2 * DINNER) + d0);
        }
    }
    float4 cwv[8]; float cbv[8];
#pragma unroll
    for (int c = 0; c < 8; ++c) {
        cwv[c] = *(const float4*)(cw + (d0 + c) * 4);
        cbv[c] = cb[d0 + c];
    }
#pragma unroll
    for (int k = 0; k < 4; ++k) {
        f16x8 o;
#pragma unroll
        for (int c = 0; c < 8; ++c) {
            float acc = cbv[c];
#pragma unroll
            for (int j = 0; j < 4; ++j) acc += cwv[c][j] * (float)wnd[k + j][c];
            float s = acc / (1.f + __expf(-acc));
            o[c] = (f16)s;
        }
        *(f16x8*)(out16 + (size_t)(row0 + k) * DINNER + d0) = o;
    }
}

// ---------------------------------------------------------------- chunked scan (split-state + FULL register staging)
__device__ inline void pow8(float e1, float* p) {
    p[0] = e1; p[1] = e1 * e1; p[2] = p[0] * p[1]; p[3] = p[1] * p[1];
    p[4] = p[0] * p[3]; p[5] = p[1] * p[3]; p[6] = p[2] * p[3]; p[7] = p[3] * p[3];
}

// pass 1: per (b, chunk, d) local scan from h=0; store end state + sum(delta)
__global__ __launch_bounds__(256) void scan_pass1(const f16x2* __restrict__ de,
                                                  const f16* __restrict__ u,
                                                  const float* __restrict__ xdbl,
                                                  const float* __restrict__ A_log,
                                                  float* __restrict__ hloc,
                                                  float* __restrict__ sumdelta) {
    __shared__ __align__(16) float bc[TCHUNK][32];
    int blk = blockIdx.x;
    int dg = blk & 7;
    int c = (blk >> 3) & (NCHUNK - 1);
    int b = blk >> 9;
    int wv = threadIdx.x >> 6, lane = threadIdx.x & 63;
    int half = lane >> 5;
    int d = dg * 128 + wv * 32 + (lane & 31);
    int n0 = half * 8;
    size_t rbase = (size_t)b * LSEQ + (size_t)c * TCHUNK;

    {   // stage B+C panel
        int trow = threadIdx.x >> 3;
        int q = (threadIdx.x & 7) << 2;
        *(float4*)&bc[trow][q] = *(const float4*)(xdbl + (rbase + trow) * 128 + 32 + q);
    }

    // full register staging of the per-thread streams (all loads in flight at once)
    const f16x2* dp = de + rbase * DINNER + d;
    const f16* up = u + rbase * DINNER + d;
    f16x2 adv[TCHUNK];
    f16 auu[TCHUNK];
#pragma unroll
    for (int t = 0; t < TCHUNK; ++t) adv[t] = dp[(size_t)t * DINNER];
#pragma unroll
    for (int t = 0; t < TCHUNK; ++t) auu[t] = up[(size_t)t * DINNER];

    float A[8];
    bool fast = true;
#pragma unroll
    for (int j = 0; j < 8; ++j) {
        float a = __expf(A_log[d * NSTATE + n0 + j]);
        A[j] = -a;
        float tgt = (float)(n0 + j + 1);
        fast = fast && (fabsf(a - tgt) <= 1e-3f * tgt);
    }
    float h[8];
#pragma unroll
    for (int j = 0; j < 8; ++j) h[j] = 0.f;

    __syncthreads();

    float sd = 0.f;
    if (fast) {
#pragma unroll
        for (int t = 0; t < TCHUNK; ++t) {
            float Bv[8]; load8(Bv, &bc[t][n0]);
            float del = (float)adv[t][0], e1 = (float)adv[t][1];
            float uu = (float)auu[t];
            sd += del;
            float du = del * uu;
            float p[8]; pow8(e1, p);
            float f = half ? p[7] : 1.f;
#pragma unroll
            for (int j = 0; j < 8; ++j)
                h[j] = (p[j] * f) * h[j] + du * Bv[j];
        }
    } else {
#pragma unroll
        for (int t = 0; t < TCHUNK; ++t) {
            float Bv[8]; load8(Bv, &bc[t][n0]);
            float del = (float)adv[t][0];
            float uu = (float)auu[t];
            sd += del;
            float du = del * uu;
#pragma unroll
            for (int j = 0; j < 8; ++j)
                h[j] = __expf(del * A[j]) * h[j] + du * Bv[j];
        }
    }
    size_t idx = ((size_t)(b * NCHUNK + c) * DINNER + d) * NSTATE + n0;
    *(float4*)(hloc + idx) = *(float4*)(h);
    *(float4*)(hloc + idx + 4) = *(float4*)(h + 4);
    if (half == 0) sumdelta[((size_t)(b * NCHUNK + c) * DINNER + d)] = sd;
}

// combine: one thread per (b,d,n); serial over chunks; IN PLACE: hloc[c] := state BEFORE chunk c
__global__ __launch_bounds__(256) void scan_combine(float* __restrict__ hloc,
                                                    const float* __restrict__ sumdelta,
                                                    const float* __restrict__ A_log) {
    int g = blockIdx.x * 256 + threadIdx.x;
    int n = g & 15;
    int d = (g >> 4) & (DINNER - 1);
    int b = g >> 14;
    float A = -__expf(A_log[d * NSTATE + n]);
    float h = 0.f;
    for (int c = 0; c < NCHUNK; ++c) {
        size_t idx = ((size_t)(b * NCHUNK + c) * DINNER + d) * NSTATE + n;
        float loc = hloc[idx];
        hloc[idx] = h;
        h = __expf(A * sumdelta[((size_t)(b * NCHUNK + c) * DINNER + d)]) * h + loc;
    }
}

// pass 2: rerun scan with true h0 (in hloc), compute y, fuse *silu(z); y16 written IN PLACE over u
__global__ __launch_bounds__(256) void scan_pass2(const f16x2* __restrict__ de,
                                                  const f16* __restrict__ u,
                                                  const float* __restrict__ xdbl,
                                                  const float* __restrict__ A_log,
                                                  const float* __restrict__ Dv,
                                                  const float* __restrict__ h0,
                                                  const f16* __restrict__ xz,
                                                  f16* __restrict__ y16) {
    __shared__ __align__(16) float bc[TCHUNK][32];
    int blk = blockIdx.x;
    int dg = blk & 7;
    int c = (blk >> 3) & (NCHUNK - 1);
    int b = blk >> 9;
    int wv = threadIdx.x >> 6, lane = threadIdx.x & 63;
    int half = lane >> 5;
    int d = dg * 128 + wv * 32 + (lane & 31);
    int n0 = half * 8;
    size_t rbase = (size_t)b * LSEQ + (size_t)c * TCHUNK;

    {
        int trow = threadIdx.x >> 3;
        int q = (threadIdx.x & 7) << 2;
        *(float4*)&bc[trow][q] = *(const float4*)(xdbl + (rbase + trow) * 128 + 32 + q);
    }

    const f16x2* dp = de + rbase * DINNER + d;
    const f16* up = u + rbase * DINNER + d;
    const f16* zp = xz + rbase * (2 * DINNER) + DINNER + d;
    f16* yp = y16 + rbase * DINNER + d;

    f16x2 adv[TCHUNK];
    f16 auu[TCHUNK];
    f16 az[TCHUNK];
#pragma unroll
    for (int t = 0; t < TCHUNK; ++t) adv[t] = dp[(size_t)t * DINNER];
#pragma unroll
    for (int t = 0; t < TCHUNK; ++t) auu[t] = up[(size_t)t * DINNER];
#pragma unroll
    for (int t = 0; t < TCHUNK; ++t) az[t] = zp[(size_t)t * (2 * DINNER)];

    float A[8];
    bool fast = true;
#pragma unroll
    for (int j = 0; j < 8; ++j) {
        float a = __expf(A_log[d * NSTATE + n0 + j]);
        A[j] = -a;
        float tgt = (float)(n0 + j + 1);
        fast = fast && (fabsf(a - tgt) <= 1e-3f * tgt);
    }
    float Dval = Dv[d];
    float h[8];
    size_t idx = ((size_t)(b * NCHUNK + c) * DINNER + d) * NSTATE + n0;
    *(float4*)(h) = *(const float4*)(h0 + idx);
    *(float4*)(h + 4) = *(const float4*)(h0 + idx + 4);

    __syncthreads();

    if (fast) {
#pragma unroll
        for (int t = 0; t < TCHUNK; ++t) {
            float Bv[8], Cv[8];
            load8(Bv, &bc[t][n0]);
            load8(Cv, &bc[t][16 + n0]);
            float del = (float)adv[t][0], e1 = (float)adv[t][1];
            float uu = (float)auu[t];
            float du = del * uu;
            float yv = 0.f;
            float p[8]; pow8(e1, p);
            float f = half ? p[7] : 1.f;
#pragma unroll
            for (int j = 0; j < 8; ++j) {
                h[j] = (p[j] * f) * h[j] + du * Bv[j];
                yv += h[j] * Cv[j];
            }
            yv += __shfl_xor(yv, 32, 64);
            yv += uu * Dval;
            float z = (float)az[t];
            float sz = z / (1.f + __expf(-z));
            if (half == 0)
                yp[(size_t)t * DINNER] = (f16)(yv * sz);
        }
    } else {
#pragma unroll
        for (int t = 0; t < TCHUNK; ++t) {
            float Bv[8], Cv[8];
            load8(Bv, &bc[t][n0]);
            load8(Cv, &bc[t][16 + n0]);
            float del = (float)adv[t][0];
            float uu = (float)auu[t];
            float du = del * uu;
            float yv = 0.f;
#pragma unroll
            for (int j = 0; j < 8; ++j) {
                h[j] = __expf(del * A[j]) * h[j] + du * Bv[j];
                yv += h[j] * Cv[j];
            }
            yv += __shfl_xor(yv, 32, 64);
            yv += uu * Dval;
            float z = (float)az[t];
            float sz = z / (1.f + __expf(-z));
            if (half == 0)
                yp[(size_t)t * DINNER] = (f16)(yv * sz);
        }
    }
}

// ---------------------------------------------------------------- fused output LNs (traw in f16, ld 768)
__global__ __launch_bounds__(256) void ln_outputs(const float* __restrict__ x,
                                                  const f16* __restrict__ traw,
                                                  const float* __restrict__ mb,
                                                  const float* __restrict__ gb,
                                                  const float* __restrict__ wm,
                                                  const float* __restrict__ bm,
                                                  const float* __restrict__ wg,
                                                  const float* __restrict__ bg,
                                                  float* __restrict__ out0,
                                                  float* __restrict__ out1) {
    int bid = blockIdx.x;
    int lane = threadIdx.x & 63;
    if (bid < NROWS / 4) {
        int row = bid * 4 + (threadIdx.x >> 6);
        f16x8 t8 = *(const f16x8*)(traw + (size_t)row * 768 + lane * 8);
        float vv[8];
#pragma unroll
        for (int j = 0; j < 8; ++j) {
            int c = lane * 8 + j;
            vv[j] = x[(size_t)row * DMODEL + c] + (float)t8[j] + mb[c];
        }
        float s = 0.f, sq = 0.f;
#pragma unroll
        for (int j = 0; j < 8; ++j) { s += vv[j]; sq += vv[j] * vv[j]; }
        s = wave_sum(s); sq = wave_sum(sq);
        float mu = s * (1.f / DMODEL);
        float rstd = rsqrtf(sq * (1.f / DMODEL) - mu * mu + LN_EPS);
        float ov[8];
#pragma unroll
        for (int j = 0; j < 8; ++j) {
            int c = lane * 8 + j;
            ov[j] = (vv[j] - mu) * rstd * wm[c] + bm[c];
        }
        float* op = out0 + (size_t)row * DMODEL + lane * 8;
        *(float4*)(op) = *(float4*)(ov);
        *(float4*)(op + 4) = *(float4*)(ov + 4);
    } else {
        const int DG = 256;
        int row = (bid - NROWS / 4) * 4 + (threadIdx.x >> 6);
        f16x4 t4 = *(const f16x4*)(traw + (size_t)row * 768 + 512 + lane * 4);
        float vv[4];
#pragma unroll
        for (int j = 0; j < 4; ++j) {
            int c = lane * 4 + j;
            vv[j] = (float)t4[j] + gb[c];
        }
        float s = 0.f, sq = 0.f;
#pragma unroll
        for (int j = 0; j < 4; ++j) { s += vv[j]; sq += vv[j] * vv[j]; }
        s = wave_sum(s); sq = wave_sum(sq);
        float mu = s * (1.f / DG);
        float rstd = rsqrtf(sq * (1.f / DG) - mu * mu + LN_EPS);
        float ov[4];
#pragma unroll
        for (int j = 0; j < 4; ++j) {
            int c = lane * 4 + j;
            ov[j] = (vv[j] - mu) * rstd * wg[c] + bg[c];
        }
        *(float4*)(out1 + (size_t)row * DG + lane * 4) = *(float4*)(ov);
    }
}

// ---------------------------------------------------------------- launcher
extern "C" void kernel_launch(void* const* d_in, const int* in_sizes, int n_in,
                              void* d_out, int out_size, void* d_ws, size_t ws_size,
                              hipStream_t stream) {
    const float* x         = (const float*)d_in[0];
    const float* norm_w    = (const float*)d_in[1];
    const float* norm_b    = (const float*)d_in[2];
    const float* in_proj_w = (const float*)d_in[3];
    const float* conv_w    = (const float*)d_in[4];
    const float* conv_b    = (const float*)d_in[5];
    const float* x_proj_w  = (const float*)d_in[6];
    const float* dt_proj_w = (const float*)d_in[7];
    const float* dt_proj_b = (const float*)d_in[8];
    const float* A_log     = (const float*)d_in[9];
    const float* Dvec      = (const float*)d_in[10];
    const float* mix_out_w = (const float*)d_in[11];
    const float* match_w   = (const float*)d_in[12];
    const float* match_b   = (const float*)d_in[13];
    const float* geom_w    = (const float*)d_in[14];
    const float* geom_b    = (const float*)d_in[15];
    const float* normm_w   = (const float*)d_in[16];
    const float* normm_b   = (const float*)d_in[17];
    const float* normg_w   = (const float*)d_in[18];
    const float* normg_b   = (const float*)d_in[19];

    char* ws = (char*)d_ws;
    f16* h16    = (f16*)(ws + 0);            // 8 MB  (reused: sumdelta during scan, hm16 after)
    f16* wip    = (f16*)(ws + 8388608);      // weights contiguous from here
    f16* wxp    = (f16*)(ws + 10485760);
    f16* wdt    = (f16*)(ws + 10747904);
    f16* wmo    = (f16*)(ws + 10813440);
    f16* wma    = (f16*)(ws + 11862016);     // match+geom contiguous: (768, 512)
    f16* xz16   = (f16*)(ws + 12648448);     // 32 MB
    f16* xmc16  = (f16*)(ws + 46202880);     // 16 MB: u (f16); pass2 writes y16 IN PLACE here
    f16* traw16 = (f16*)(ws + 62980096);     // 12.6 MB: traw (8192x768 f16)
    float* xdbl = (float*)(ws + 96534528);   // 4 MB
    f16* dt16   = (f16*)(ws + 100728832);    // 512 KB
    f16x2* de   = (f16x2*)(ws + 101253120);  // 32 MB: packed {delta, exp(-delta)}

    float* hloc     = (float*)d_out;         // 16.8 MB scratch in d_out (25.2 MB)
    float* sumdelta = (float*)h16;

    f16* hm16 = h16;
    f16* y16 = xmc16;                        // in-place over u
    float* out0 = (float*)d_out;
    float* out1 = out0 + (size_t)NROWS * DMODEL;

    // 1. LN(x) -> h16  +  weight conversions (fused)
    prep<<<NROWS / 4 + 1024, 256, 0, stream>>>(x, norm_w, norm_b, h16,
                                               in_proj_w, x_proj_w, dt_proj_w,
                                               mix_out_w, match_w, geom_w, wip);
    // 2. xz = h @ in_proj^T
    gemm_xwt<1><<<dim3(16, 64), 256, 0, stream>>>(h16, wip, xz16, 512, 2048, nullptr);
    // 3. conv + silu -> u (f16)
    conv_silu<<<1024, 256, 0, stream>>>(xz16, conv_w, conv_b, xmc16);
    // 4. x_dbl = xm @ x_proj^T (f32 ld128) + dt16 fused
    gemm_xwt<3><<<dim3(1, 64), 256, 0, stream>>>(xmc16, wxp, xdbl, 1024, 128, dt16);
    // 5. de = {softplus, exp(-softplus)} via dedicated small-K kernel
    dt_delta<<<dim3(4, 128), 256, 0, stream>>>(dt16, wdt, dt_proj_b, de);
    // 6. chunked selective scan (split-state, full register staging)
    scan_pass1<<<NB * NCHUNK * 8, 256, 0, stream>>>(de, xmc16, xdbl, A_log, hloc, sumdelta);
    scan_combine<<<NB * DINNER * NSTATE / 256, 256, 0, stream>>>(hloc, sumdelta, A_log);
    scan_pass2<<<NB * NCHUNK * 8, 256, 0, stream>>>(de, xmc16, xdbl, A_log, Dvec, hloc, xz16, y16);
    // 7. hm = y @ mix_out^T
    gemm_xwt<1><<<dim3(4, 64), 256, 0, stream>>>(y16, wmo, hm16, 1024, 512, nullptr);
    // 8. match+geom fused GEMM (N=768, f16 out)
    gemm_xwt<1><<<dim3(6, 64), 256, 0, stream>>>(hm16, wma, traw16, 512, 768, nullptr);
    // 9. fused output layernorms (d_out; hloc dead by now)
    ln_outputs<<<NROWS / 2, 256, 0, stream>>>(x, traw16, match_b, geom_b,
                                              normm_w, normm_b, normg_w, normg_b, out0, out1);
}

// Round 12
// 297.023 us; speedup vs baseline: 1.5014x; 1.0301x over previous
//
#include <hip/hip_runtime.h>
#include <hip/hip_bf16.h>

#define NB 4
#define LSEQ 2048
#define NROWS (NB * LSEQ)        // 8192
#define DMODEL 512
#define DINNER 1024
#define NSTATE 16
#define DTRANK 32
#define LN_EPS 1e-5f

#define NCHUNK 64
#define TCHUNK 32               // NCHUNK * TCHUNK == LSEQ

typedef _Float16 f16;
typedef _Float16 f16x2 __attribute__((ext_vector_type(2)));
typedef _Float16 f16x4 __attribute__((ext_vector_type(4)));
typedef _Float16 f16x8 __attribute__((ext_vector_type(8)));
typedef float f32x4 __attribute__((ext_vector_type(4)));

#define AS1 __attribute__((address_space(1)))
#define AS3 __attribute__((address_space(3)))

// ---------------------------------------------------------------- utilities
__device__ inline float wave_sum(float v) {
#pragma unroll
    for (int off = 32; off; off >>= 1) v += __shfl_xor(v, off, 64);
    return v;
}

__device__ inline void load8(float* dst, const float* src) {
    float4* d4 = (float4*)dst; const float4* s4 = (const float4*)src;
    d4[0] = s4[0]; d4[1] = s4[1];
}

// ---------------------------------------------------------------- prep: LN(x)->f16  +  all weight cvt
__global__ __launch_bounds__(256) void prep(const float* __restrict__ x,
                                            const float* __restrict__ w,
                                            const float* __restrict__ b,
                                            f16* __restrict__ out,
                                            const float* __restrict__ ip, const float* __restrict__ xp,
                                            const float* __restrict__ dt, const float* __restrict__ mo,
                                            const float* __restrict__ ma, const float* __restrict__ ge,
                                            f16* __restrict__ wout) {
    if (blockIdx.x < NROWS / 4) {
        int row = blockIdx.x * 4 + (threadIdx.x >> 6);
        int lane = threadIdx.x & 63;
        const float* xr = x + (size_t)row * DMODEL + lane * 8;
        float vv[8];
        *(float4*)(vv) = *(const float4*)(xr);
        *(float4*)(vv + 4) = *(const float4*)(xr + 4);
        float s = 0.f, sq = 0.f;
#pragma unroll
        for (int j = 0; j < 8; ++j) { s += vv[j]; sq += vv[j] * vv[j]; }
        s = wave_sum(s); sq = wave_sum(sq);
        float mu = s * (1.f / DMODEL);
        float rstd = rsqrtf(sq * (1.f / DMODEL) - mu * mu + LN_EPS);
        f16x8 o;
#pragma unroll
        for (int j = 0; j < 8; ++j) {
            int c = lane * 8 + j;
            o[j] = (f16)((vv[j] - mu) * rstd * w[c] + b[c]);
        }
        *(f16x8*)(out + (size_t)row * DMODEL + lane * 8) = o;
    } else {
        int i = (blockIdx.x - NROWS / 4) * 256 + threadIdx.x;
        int stride = (gridDim.x - NROWS / 4) * 256;
        for (; i < 2129920; i += stride) {
            float v;
            if (i < 1048576) v = ip[i];
            else if (i < 1179648) { int j = i - 1048576; v = (j < 65536) ? xp[j] : 0.f; }
            else if (i < 1212416) v = dt[i - 1179648];
            else if (i < 1736704) v = mo[i - 1212416];
            else if (i < 1998848) v = ma[i - 1736704];
            else v = ge[i - 1998848];
            wout[i] = (f16)v;
        }
    }
}

// ---------------------------------------------------------------- GEMM: C[M,N] = X[M,K] @ W[N,K]^T
// 128x128 tile, BK=32, 4 waves; global_load_lds staging; 3-deep counted-vmcnt pipeline;
// XCD-chunked block swizzle (T1); MODE 1 epilogue: LDS-transposed fully-coalesced f16 stores.
// MODE 1: f16 out | 3: f32 out(ld128) + f16 aux col<32
template <int MODE>
__global__ __launch_bounds__(256) void gemm_xwt(const f16* __restrict__ X,
                                                const f16* __restrict__ W,
                                                void* __restrict__ Out,
                                                int K, int ldc,
                                                f16* __restrict__ aux) {
    __shared__ __align__(16) f16 smem[4][128 * 32];   // As=smem[0..1], Bs=smem[2..3]; reused as C-tile
    const int tid = threadIdx.x;
    const int lane = tid & 63;
    const int wv = tid >> 6;
    const int wr = wv >> 1, wc = wv & 1;

    // XCD-chunked swizzle: each XCD gets a contiguous 1/8 of the grid (L2 residency)
    int nwg = gridDim.x * gridDim.y;
    int id = blockIdx.y * gridDim.x + blockIdx.x;
    int sw = (id & 7) * (nwg >> 3) + (id >> 3);
    int bx = sw % gridDim.x;
    int by = sw / gridDim.x;
    const int rowbase = by * 128;
    const int colbase = bx * 128;

    const f32x4 zero = {0.f, 0.f, 0.f, 0.f};
    f32x4 acc[4][4];
#pragma unroll
    for (int m = 0; m < 4; ++m)
#pragma unroll
        for (int n = 0; n < 4; ++n) acc[m][n] = zero;

    const int nk = K >> 5;
    auto stage = [&](int buf, int kt) {
        const int k0 = kt << 5;
#pragma unroll
        for (int it = 0; it < 2; ++it) {
            int iid = it * 256 + wv * 64 + lane;
            int row = iid >> 2;
            int k8 = (iid & 3) << 3;
            const f16* ga = X + (size_t)(rowbase + row) * K + k0 + k8;
            const f16* gb = W + (size_t)(colbase + row) * K + k0 + k8;
            __builtin_amdgcn_global_load_lds(
                (const AS1 void*)ga,
                (AS3 void*)(&smem[buf][(it * 256 + wv * 64) * 8]), 16, 0, 0);
            __builtin_amdgcn_global_load_lds(
                (const AS1 void*)gb,
                (AS3 void*)(&smem[2 + buf][(it * 256 + wv * 64) * 8]), 16, 0, 0);
        }
    };

    stage(0, 0);
    if (nk > 1) stage(1, 1);
    for (int kt = 0; kt < nk; ++kt) {
        const int cur = kt & 1;
        if (kt + 1 < nk) { asm volatile("s_waitcnt vmcnt(4)" ::: "memory"); }
        else             { asm volatile("s_waitcnt vmcnt(0)" ::: "memory"); }
        asm volatile("s_barrier" ::: "memory");

        f16x8 af[4], bf[4];
#pragma unroll
        for (int m = 0; m < 4; ++m)
            af[m] = *(const f16x8*)(&smem[cur][(wr * 64 + m * 16 + (lane & 15)) * 32 + ((lane >> 4) << 3)]);
#pragma unroll
        for (int n = 0; n < 4; ++n)
            bf[n] = *(const f16x8*)(&smem[2 + cur][(wc * 64 + n * 16 + (lane & 15)) * 32 + ((lane >> 4) << 3)]);
#pragma unroll
        for (int m = 0; m < 4; ++m)
#pragma unroll
            for (int n = 0; n < 4; ++n)
                acc[m][n] = __builtin_amdgcn_mfma_f32_16x16x32_f16(af[m], bf[n], acc[m][n], 0, 0, 0);

        asm volatile("s_waitcnt lgkmcnt(0)" ::: "memory");
        asm volatile("s_barrier" ::: "memory");
        if (kt + 2 < nk) stage(cur, kt + 2);
    }

    if (MODE == 1) {
        // ---- coalesced epilogue: acc -> LDS (XOR-swizzled) -> row-major 16B stores
        char* Cs = (char*)&smem[0][0];          // 32 KB == 128x128 f16
#pragma unroll
        for (int m = 0; m < 4; ++m) {
#pragma unroll
            for (int n = 0; n < 4; ++n) {
#pragma unroll
                for (int r = 0; r < 4; ++r) {
                    int row = wr * 64 + m * 16 + ((lane >> 4) << 2) + r;
                    int col = wc * 64 + n * 16 + (lane & 15);
                    int bo = (row << 8) + (col << 1);
                    bo ^= (row & 7) << 4;
                    *(f16*)(Cs + bo) = (f16)acc[m][n][r];
                }
            }
        }
        __syncthreads();
#pragma unroll
        for (int it = 0; it < 8; ++it) {
            int iid = it * 256 + tid;
            int row = iid >> 4;
            int ch = iid & 15;
            int bo = (row << 8) + (ch << 4);
            bo ^= (row & 7) << 4;
            f16x8 v = *(f16x8*)(Cs + bo);
            *(f16x8*)((f16*)Out + (size_t)(rowbase + row) * ldc + colbase + ch * 8) = v;
        }
    } else {
#pragma unroll
        for (int m = 0; m < 4; ++m) {
            int r0 = rowbase + wr * 64 + m * 16 + ((lane >> 4) << 2);
#pragma unroll
            for (int n = 0; n < 4; ++n) {
                int c = colbase + wc * 64 + n * 16 + (lane & 15);
#pragma unroll
                for (int r = 0; r < 4; ++r) {
                    float v = acc[m][n][r];
                    ((float*)Out)[(size_t)(r0 + r) * ldc + c] = v;
                    if (c < DTRANK) aux[(size_t)(r0 + r) * DTRANK + c] = (f16)v;
                }
            }
        }
    }
}

// ---------------------------------------------------------------- dt_proj + softplus (dedicated small-K kernel)
__global__ __launch_bounds__(256) void dt_delta(const f16* __restrict__ dt16,  // (8192, 32)
                                                const f16* __restrict__ wdt,   // (1024, 32)
                                                const float* __restrict__ bias,
                                                f16x2* __restrict__ de) {      // (8192, 1024)
    __shared__ float sdt[64][32];        // 8 KB
    int c = blockIdx.x * 256 + threadIdx.x;
    int r0 = blockIdx.y * 64;
    {
        int row = threadIdx.x >> 2;
        int q = (threadIdx.x & 3) * 8;
        f16x8 v = *(const f16x8*)(dt16 + (size_t)(r0 + row) * DTRANK + q);
#pragma unroll
        for (int j = 0; j < 8; ++j) sdt[row][q + j] = (float)v[j];
    }
    float wv[32];
#pragma unroll
    for (int qq = 0; qq < 4; ++qq) {
        f16x8 v = *(const f16x8*)(wdt + (size_t)c * DTRANK + qq * 8);
#pragma unroll
        for (int j = 0; j < 8; ++j) wv[qq * 8 + j] = (float)v[j];
    }
    float bs = bias[c];
    __syncthreads();

    for (int r = 0; r < 64; ++r) {
        float acc = bs;
#pragma unroll
        for (int k = 0; k < 32; ++k) acc += sdt[r][k] * wv[k];
        float dl, e1;
        if (acc > 20.f) {                      // softplus(t)≈t; avoid exp overflow
            dl = acc; e1 = __expf(-acc);
        } else {
            float et = __expf(acc);
            e1 = 1.f / (1.f + et);             // exp(-softplus(t)) = sigmoid(-t)
            dl = -__logf(e1);                  // softplus(t)
        }
        f16x2 pk; pk[0] = (f16)dl; pk[1] = (f16)e1;
        de[(size_t)(r0 + r) * DINNER + c] = pk;
    }
}

// ---------------------------------------------------------------- causal depthwise conv + silu
__global__ __launch_bounds__(256) void conv_silu(const f16* __restrict__ xz,
                                                 const float* __restrict__ cw,
                                                 const float* __restrict__ cb,
                                                 f16* __restrict__ out16) {
    int i = blockIdx.x * 256 + threadIdx.x;          // 0 .. 262143
    int dg = i & 127;                                // channel group (8 ch)
    int rg = i >> 7;                                 // row group (4 rows)
    int row0 = rg * 4;
    int t0 = row0 & (LSEQ - 1);
    int d0 = dg * 8;

    f16x8 wnd[7];
#pragma unroll
    for (int j = 0; j < 7; ++j) {
        if (j < 3 && t0 == 0) {
#pragma unroll
            for (int c = 0; c < 8; ++c) wnd[j][c] = (f16)0.f;
        } else {
            wnd[j] = *(const f16x8*)(xz + (size_t)(row0 - 3 + j) * (2 * DINNER) + d0);
        }
    }
    float4 cwv[8]; float cbv[8];
#pragma unroll
    for (int c = 0; c < 8; ++c) {
        cwv[c] = *(const float4*)(cw + (d0 + c) * 4);
        cbv[c] = cb[d0 + c];
    }
#pragma unroll
    for (int k = 0; k < 4; ++k) {
        f16x8 o;
#pragma unroll
        for (int c = 0; c < 8; ++c) {
            float acc = cbv[c];
#pragma unroll
            for (int j = 0; j < 4; ++j) acc += cwv[c][j] * (float)wnd[k + j][c];
            float s = acc / (1.f + __expf(-acc));
            o[c] = (f16)s;
        }
        *(f16x8*)(out16 + (size_t)(row0 + k) * DINNER + d0) = o;
    }
}

// ---------------------------------------------------------------- chunked scan (split-state + FULL register staging)
__device__ inline void pow8(float e1, float* p) {
    p[0] = e1; p[1] = e1 * e1; p[2] = p[0] * p[1]; p[3] = p[1] * p[1];
    p[4] = p[0] * p[3]; p[5] = p[1] * p[3]; p[6] = p[2] * p[3]; p[7] = p[3] * p[3];
}

// pass 1: per (b, chunk, d) local scan from h=0; store end state + sum(delta)
__global__ __launch_bounds__(256) void scan_pass1(const f16x2* __restrict__ de,
                                                  const f16* __restrict__ u,
                                                  const float* __restrict__ xdbl,
                                                  const float* __restrict__ A_log,
                                                  float* __restrict__ hloc,
                                                  float* __restrict__ sumdelta) {
    __shared__ __align__(16) float bc[TCHUNK][32];
    int blk = blockIdx.x;
    int dg = blk & 7;
    int c = (blk >> 3) & (NCHUNK - 1);
    int b = blk >> 9;
    int wv = threadIdx.x >> 6, lane = threadIdx.x & 63;
    int half = lane >> 5;
    int d = dg * 128 + wv * 32 + (lane & 31);
    int n0 = half * 8;
    size_t rbase = (size_t)b * LSEQ + (size_t)c * TCHUNK;

    {   // stage B+C panel
        int trow = threadIdx.x >> 3;
        int q = (threadIdx.x & 7) << 2;
        *(float4*)&bc[trow][q] = *(const float4*)(xdbl + (rbase + trow) * 128 + 32 + q);
    }

    // full register staging of the per-thread streams (all loads in flight at once)
    const f16x2* dp = de + rbase * DINNER + d;
    const f16* up = u + rbase * DINNER + d;
    f16x2 adv[TCHUNK];
    f16 auu[TCHUNK];
#pragma unroll
    for (int t = 0; t < TCHUNK; ++t) adv[t] = dp[(size_t)t * DINNER];
#pragma unroll
    for (int t = 0; t < TCHUNK; ++t) auu[t] = up[(size_t)t * DINNER];

    float A[8];
    bool fast = true;
#pragma unroll
    for (int j = 0; j < 8; ++j) {
        float a = __expf(A_log[d * NSTATE + n0 + j]);
        A[j] = -a;
        float tgt = (float)(n0 + j + 1);
        fast = fast && (fabsf(a - tgt) <= 1e-3f * tgt);
    }
    float h[8];
#pragma unroll
    for (int j = 0; j < 8; ++j) h[j] = 0.f;

    __syncthreads();

    float sd = 0.f;
    if (fast) {
#pragma unroll
        for (int t = 0; t < TCHUNK; ++t) {
            float Bv[8]; load8(Bv, &bc[t][n0]);
            float del = (float)adv[t][0], e1 = (float)adv[t][1];
            float uu = (float)auu[t];
            sd += del;
            float du = del * uu;
            float p[8]; pow8(e1, p);
            float f = half ? p[7] : 1.f;
#pragma unroll
            for (int j = 0; j < 8; ++j)
                h[j] = (p[j] * f) * h[j] + du * Bv[j];
        }
    } else {
#pragma unroll
        for (int t = 0; t < TCHUNK; ++t) {
            float Bv[8]; load8(Bv, &bc[t][n0]);
            float del = (float)adv[t][0];
            float uu = (float)auu[t];
            sd += del;
            float du = del * uu;
#pragma unroll
            for (int j = 0; j < 8; ++j)
                h[j] = __expf(del * A[j]) * h[j] + du * Bv[j];
        }
    }
    size_t idx = ((size_t)(b * NCHUNK + c) * DINNER + d) * NSTATE + n0;
    *(float4*)(hloc + idx) = *(float4*)(h);
    *(float4*)(hloc + idx + 4) = *(float4*)(h + 4);
    if (half == 0) sumdelta[((size_t)(b * NCHUNK + c) * DINNER + d)] = sd;
}

// combine: one thread per (b,d,n); serial over chunks; IN PLACE: hloc[c] := state BEFORE chunk c
__global__ __launch_bounds__(256) void scan_combine(float* __restrict__ hloc,
                                                    const float* __restrict__ sumdelta,
                                                    const float* __restrict__ A_log) {
    int g = blockIdx.x * 256 + threadIdx.x;
    int n = g & 15;
    int d = (g >> 4) & (DINNER - 1);
    int b = g >> 14;
    float A = -__expf(A_log[d * NSTATE + n]);
    float h = 0.f;
    for (int c = 0; c < NCHUNK; ++c) {
        size_t idx = ((size_t)(b * NCHUNK + c) * DINNER + d) * NSTATE + n;
        float loc = hloc[idx];
        hloc[idx] = h;
        h = __expf(A * sumdelta[((size_t)(b * NCHUNK + c) * DINNER + d)]) * h + loc;
    }
}

// pass 2: rerun scan with true h0 (in hloc), compute y, fuse *silu(z); y16 written IN PLACE over u
__global__ __launch_bounds__(256) void scan_pass2(const f16x2* __restrict__ de,
                                                  const f16* __restrict__ u,
                                                  const float* __restrict__ xdbl,
                                                  const float* __restrict__ A_log,
                                                  const float* __restrict__ Dv,
                                                  const float* __restrict__ h0,
                                                  const f16* __restrict__ xz,
                                                  f16* __restrict__ y16) {
    __shared__ __align__(16) float bc[TCHUNK][32];
    int blk = blockIdx.x;
    int dg = blk & 7;
    int c = (blk >> 3) & (NCHUNK - 1);
    int b = blk >> 9;
    int wv = threadIdx.x >> 6, lane = threadIdx.x & 63;
    int half = lane >> 5;
    int d = dg * 128 + wv * 32 + (lane & 31);
    int n0 = half * 8;
    size_t rbase = (size_t)b * LSEQ + (size_t)c * TCHUNK;

    {
        int trow = threadIdx.x >> 3;
        int q = (threadIdx.x & 7) << 2;
        *(float4*)&bc[trow][q] = *(const float4*)(xdbl + (rbase + trow) * 128 + 32 + q);
    }

    const f16x2* dp = de + rbase * DINNER + d;
    const f16* up = u + rbase * DINNER + d;
    const f16* zp = xz + rbase * (2 * DINNER) + DINNER + d;
    f16* yp = y16 + rbase * DINNER + d;

    f16x2 adv[TCHUNK];
    f16 auu[TCHUNK];
    f16 az[TCHUNK];
#pragma unroll
    for (int t = 0; t < TCHUNK; ++t) adv[t] = dp[(size_t)t * DINNER];
#pragma unroll
    for (int t = 0; t < TCHUNK; ++t) auu[t] = up[(size_t)t * DINNER];
#pragma unroll
    for (int t = 0; t < TCHUNK; ++t) az[t] = zp[(size_t)t * (2 * DINNER)];

    float A[8];
    bool fast = true;
#pragma unroll
    for (int j = 0; j < 8; ++j) {
        float a = __expf(A_log[d * NSTATE + n0 + j]);
        A[j] = -a;
        float tgt = (float)(n0 + j + 1);
        fast = fast && (fabsf(a - tgt) <= 1e-3f * tgt);
    }
    float Dval = Dv[d];
    float h[8];
    size_t idx = ((size_t)(b * NCHUNK + c) * DINNER + d) * NSTATE + n0;
    *(float4*)(h) = *(const float4*)(h0 + idx);
    *(float4*)(h + 4) = *(const float4*)(h0 + idx + 4);

    __syncthreads();

    if (fast) {
#pragma unroll
        for (int t = 0; t < TCHUNK; ++t) {
            float Bv[8], Cv[8];
            load8(Bv, &bc[t][n0]);
            load8(Cv, &bc[t][16 + n0]);
            float del = (float)adv[t][0], e1 = (float)adv[t][1];
            float uu = (float)auu[t];
            float du = del * uu;
            float yv = 0.f;
            float p[8]; pow8(e1, p);
            float f = half ? p[7] : 1.f;
#pragma unroll
            for (int j = 0; j < 8; ++j) {
                h[j] = (p[j] * f) * h[j] + du * Bv[j];
                yv += h[j] * Cv[j];
            }
            yv += __shfl_xor(yv, 32, 64);
            yv += uu * Dval;
            float z = (float)az[t];
            float sz = z / (1.f + __expf(-z));
            if (half == 0)
                yp[(size_t)t * DINNER] = (f16)(yv * sz);
        }
    } else {
#pragma unroll
        for (int t = 0; t < TCHUNK; ++t) {
            float Bv[8], Cv[8];
            load8(Bv, &bc[t][n0]);
            load8(Cv, &bc[t][16 + n0]);
            float del = (float)adv[t][0];
            float uu = (float)auu[t];
            float du = del * uu;
            float yv = 0.f;
#pragma unroll
            for (int j = 0; j < 8; ++j) {
                h[j] = __expf(del * A[j]) * h[j] + du * Bv[j];
                yv += h[j] * Cv[j];
            }
            yv += __shfl_xor(yv, 32, 64);
            yv += uu * Dval;
            float z = (float)az[t];
            float sz = z / (1.f + __expf(-z));
            if (half == 0)
                yp[(size_t)t * DINNER] = (f16)(yv * sz);
        }
    }
}

// ---------------------------------------------------------------- fused output LNs (traw in f16, ld 768)
__global__ __launch_bounds__(256) void ln_outputs(const float* __restrict__ x,
                                                  const f16* __restrict__ traw,
                                                  const float* __restrict__ mb,
                                                  const float* __restrict__ gb,
                                                  const float* __restrict__ wm,
                                                  const float* __restrict__ bm,
                                                  const float* __restrict__ wg,
                                                  const float* __restrict__ bg,
                                                  float* __restrict__ out0,
                                                  float* __restrict__ out1) {
    int bid = blockIdx.x;
    int lane = threadIdx.x & 63;
    if (bid < NROWS / 4) {
        int row = bid * 4 + (threadIdx.x >> 6);
        f16x8 t8 = *(const f16x8*)(traw + (size_t)row * 768 + lane * 8);
        float vv[8];
#pragma unroll
        for (int j = 0; j < 8; ++j) {
            int c = lane * 8 + j;
            vv[j] = x[(size_t)row * DMODEL + c] + (float)t8[j] + mb[c];
        }
        float s = 0.f, sq = 0.f;
#pragma unroll
        for (int j = 0; j < 8; ++j) { s += vv[j]; sq += vv[j] * vv[j]; }
        s = wave_sum(s); sq = wave_sum(sq);
        float mu = s * (1.f / DMODEL);
        float rstd = rsqrtf(sq * (1.f / DMODEL) - mu * mu + LN_EPS);
        float ov[8];
#pragma unroll
        for (int j = 0; j < 8; ++j) {
            int c = lane * 8 + j;
            ov[j] = (vv[j] - mu) * rstd * wm[c] + bm[c];
        }
        float* op = out0 + (size_t)row * DMODEL + lane * 8;
        *(float4*)(op) = *(float4*)(ov);
        *(float4*)(op + 4) = *(float4*)(ov + 4);
    } else {
        const int DG = 256;
        int row = (bid - NROWS / 4) * 4 + (threadIdx.x >> 6);
        f16x4 t4 = *(const f16x4*)(traw + (size_t)row * 768 + 512 + lane * 4);
        float vv[4];
#pragma unroll
        for (int j = 0; j < 4; ++j) {
            int c = lane * 4 + j;
            vv[j] = (float)t4[j] + gb[c];
        }
        float s = 0.f, sq = 0.f;
#pragma unroll
        for (int j = 0; j < 4; ++j) { s += vv[j]; sq += vv[j] * vv[j]; }
        s = wave_sum(s); sq = wave_sum(sq);
        float mu = s * (1.f / DG);
        float rstd = rsqrtf(sq * (1.f / DG) - mu * mu + LN_EPS);
        float ov[4];
#pragma unroll
        for (int j = 0; j < 4; ++j) {
            int c = lane * 4 + j;
            ov[j] = (vv[j] - mu) * rstd * wg[c] + bg[c];
        }
        *(float4*)(out1 + (size_t)row * DG + lane * 4) = *(float4*)(ov);
    }
}

// ---------------------------------------------------------------- launcher
extern "C" void kernel_launch(void* const* d_in, const int* in_sizes, int n_in,
                              void* d_out, int out_size, void* d_ws, size_t ws_size,
                              hipStream_t stream) {
    const float* x         = (const float*)d_in[0];
    const float* norm_w    = (const float*)d_in[1];
    const float* norm_b    = (const float*)d_in[2];
    const float* in_proj_w = (const float*)d_in[3];
    const float* conv_w    = (const float*)d_in[4];
    const float* conv_b    = (const float*)d_in[5];
    const float* x_proj_w  = (const float*)d_in[6];
    const float* dt_proj_w = (const float*)d_in[7];
    const float* dt_proj_b = (const float*)d_in[8];
    const float* A_log     = (const float*)d_in[9];
    const float* Dvec      = (const float*)d_in[10];
    const float* mix_out_w = (const float*)d_in[11];
    const float* match_w   = (const float*)d_in[12];
    const float* match_b   = (const float*)d_in[13];
    const float* geom_w    = (const float*)d_in[14];
    const float* geom_b    = (const float*)d_in[15];
    const float* normm_w   = (const float*)d_in[16];
    const float* normm_b   = (const float*)d_in[17];
    const float* normg_w   = (const float*)d_in[18];
    const float* normg_b   = (const float*)d_in[19];

    char* ws = (char*)d_ws;
    f16* h16    = (f16*)(ws + 0);            // 8 MB  (reused: sumdelta during scan, hm16 after)
    f16* wip    = (f16*)(ws + 8388608);      // weights contiguous from here
    f16* wxp    = (f16*)(ws + 10485760);
    f16* wdt    = (f16*)(ws + 10747904);
    f16* wmo    = (f16*)(ws + 10813440);
    f16* wma    = (f16*)(ws + 11862016);     // match+geom contiguous: (768, 512)
    f16* xz16   = (f16*)(ws + 12648448);     // 32 MB
    f16* xmc16  = (f16*)(ws + 46202880);     // 16 MB: u (f16); pass2 writes y16 IN PLACE here
    f16* traw16 = (f16*)(ws + 62980096);     // 12.6 MB: traw (8192x768 f16)
    float* xdbl = (float*)(ws + 96534528);   // 4 MB
    f16* dt16   = (f16*)(ws + 100728832);    // 512 KB
    f16x2* de   = (f16x2*)(ws + 101253120);  // 32 MB: packed {delta, exp(-delta)}

    float* hloc     = (float*)d_out;         // 16.8 MB scratch in d_out (25.2 MB)
    float* sumdelta = (float*)h16;

    f16* hm16 = h16;
    f16* y16 = xmc16;                        // in-place over u
    float* out0 = (float*)d_out;
    float* out1 = out0 + (size_t)NROWS * DMODEL;

    // 1. LN(x) -> h16  +  weight conversions (fused)
    prep<<<NROWS / 4 + 1024, 256, 0, stream>>>(x, norm_w, norm_b, h16,
                                               in_proj_w, x_proj_w, dt_proj_w,
                                               mix_out_w, match_w, geom_w, wip);
    // 2. xz = h @ in_proj^T
    gemm_xwt<1><<<dim3(16, 64), 256, 0, stream>>>(h16, wip, xz16, 512, 2048, nullptr);
    // 3. conv + silu -> u (f16)
    conv_silu<<<1024, 256, 0, stream>>>(xz16, conv_w, conv_b, xmc16);
    // 4. x_dbl = xm @ x_proj^T (f32 ld128) + dt16 fused
    gemm_xwt<3><<<dim3(1, 64), 256, 0, stream>>>(xmc16, wxp, xdbl, 1024, 128, dt16);
    // 5. de = {softplus, exp(-softplus)} via dedicated small-K kernel
    dt_delta<<<dim3(4, 128), 256, 0, stream>>>(dt16, wdt, dt_proj_b, de);
    // 6. chunked selective scan (split-state, full register staging)
    scan_pass1<<<NB * NCHUNK * 8, 256, 0, stream>>>(de, xmc16, xdbl, A_log, hloc, sumdelta);
    scan_combine<<<NB * DINNER * NSTATE / 256, 256, 0, stream>>>(hloc, sumdelta, A_log);
    scan_pass2<<<NB * NCHUNK * 8, 256, 0, stream>>>(de, xmc16, xdbl, A_log, Dvec, hloc, xz16, y16);
    // 7. hm = y @ mix_out^T
    gemm_xwt<1><<<dim3(4, 64), 256, 0, stream>>>(y16, wmo, hm16, 1024, 512, nullptr);
    // 8. match+geom fused GEMM (N=768, f16 out)
    gemm_xwt<1><<<dim3(6, 64), 256, 0, stream>>>(hm16, wma, traw16, 512, 768, nullptr);
    // 9. fused output layernorms (d_out; hloc dead by now)
    ln_outputs<<<NROWS / 2, 256, 0, stream>>>(x, traw16, match_b, geom_b,
                                              normm_w, normm_b, normg_w, normg_b, out0, out1);
}